// Round 2
// baseline (3185.159 us; speedup 1.0000x reference)
//
#include <hip/hip_runtime.h>
#include <hip/hip_fp16.h>

typedef unsigned int  u32;
typedef unsigned short u16;

typedef _Float16 h2v __attribute__((ext_vector_type(2)));
typedef _Float16 h4v __attribute__((ext_vector_type(4)));
typedef float    f4v __attribute__((ext_vector_type(4)));

// ---------- helpers ----------
static __device__ __forceinline__ u16 f2h_bits(float x){
    _Float16 h = (_Float16)x;
    return __builtin_bit_cast(u16, h);
}
static __device__ __forceinline__ u32 pack2(float a, float b){
    return (u32)f2h_bits(a) | ((u32)f2h_bits(b) << 16);
}
static __device__ __forceinline__ float fdot2(u32 w, u32 h, float acc){
#if __has_builtin(__builtin_amdgcn_fdot2)
    return __builtin_amdgcn_fdot2(__builtin_bit_cast(h2v, w),
                                  __builtin_bit_cast(h2v, h), acc, false);
#else
    h2v wv = __builtin_bit_cast(h2v, w), hv = __builtin_bit_cast(h2v, h);
    return acc + (float)wv[0]*(float)hv[0] + (float)wv[1]*(float)hv[1];
#endif
}
static __device__ __forceinline__ float sigm(float x){
    return 1.f / (1.f + __expf(-x));
}
static __device__ __forceinline__ float tanh_fast(float x){
    return 1.f - 2.f / (__expf(2.f*x) + 1.f);
}

// B=128, T=512, D=H=256, 4H=1024; beta in [0,256): beta<128 -> input1, else input2

// ---------- kernel: convert weights ----------
// wih16: [l][g][d] fp16 (flat cast of W_ih)
// whhT : [l][p][r] u32, p = column-pair (0..127), r = gate row (0..1023)
//        whhT[l][p][r] packs (Whh[l][r][2p], Whh[l][r][2p+1])
// bias : [l][g] = b_ih + b_hh
__global__ void cvt_weights(const float* __restrict__ Wih,
                            const float* __restrict__ Whh,
                            const float* __restrict__ bih,
                            const float* __restrict__ bhh,
                            u32* __restrict__ wih16u,   // 262144 u32
                            u32* __restrict__ whhT,     // 262144 u32
                            float* __restrict__ bias){  // 2048
    u32 e = blockIdx.x * blockDim.x + threadIdx.x;      // 0 .. 262143
    {
        float2 v = ((const float2*)Wih)[e];
        wih16u[e] = pack2(v.x, v.y);
    }
    {
        u32 l = e >> 17, rem = e & 131071u;
        u32 p = rem >> 10, r = rem & 1023u;
        float2 v = ((const float2*)Whh)[(size_t)(l*1024u + r)*128u + p];
        whhT[e] = pack2(v.x, v.y);
    }
    if (e < 2048u) bias[e] = bih[e] + bhh[e];
}

// ---------- projection GEMM:  C[Mc,1024] = A[Mc,256] * B[1024,256]^T ----------
// Mc = 256 betas * Tc rows, row m -> beta = m>>lgTc, tc = m & (Tc-1).
// A_FP32=1: A row = input fp32 (in1/in2, timestep t0+tc), converted on load.
// A_FP32=0: A row = A16 + m*256 (fp16, hseq chunk).
// 128x128 tile / 4 waves / v_mfma_f32_16x16x16_f16; grid = (8 Ntiles, Mc/128).
template<int A_FP32>
__global__ __launch_bounds__(256) void proj_gemm(
        const float* __restrict__ in1, const float* __restrict__ in2,
        const u16*  __restrict__ A16,
        const u16*  __restrict__ Bw,      // [1024][256] fp16 = W_ih[l]
        u16*        __restrict__ Cout,    // [Mc][1024] fp16
        int t0, int lgTc){
    __shared__ u16 Blds[128][260];        // +4 halves pad
    const int tid = threadIdx.x;
    const int n0 = blockIdx.x * 128;
    const int m0 = blockIdx.y * 128;

    {   // stage B tile (128 rows x 128 u32), coalesced
        const u32* src = (const u32*)Bw;
        #pragma unroll
        for (int i = 0; i < 64; i++){
            int idx = i*256 + tid;
            int r  = idx >> 7;
            int cu = idx & 127;
            u32 v = src[(size_t)(n0 + r)*128 + cu];
            *(u32*)&Blds[r][cu*2] = v;
        }
    }
    __syncthreads();

    const int l   = tid & 63;
    const int wid = tid >> 6;
    const int wm = (wid >> 1) * 64;
    const int wn = (wid & 1) * 64;
    const int lr = l & 15;
    const int lk = l >> 4;

    f4v acc[4][4] = {};

    const float* a32[4];
    const u16*   a16[4];
    #pragma unroll
    for (int f = 0; f < 4; f++){
        int m = m0 + wm + f*16 + lr;
        if (A_FP32){
            int beta = m >> lgTc;
            int tc   = m & ((1 << lgTc) - 1);
            const float* base = (beta < 128) ? in1 : in2;
            a32[f] = base + ((size_t)(beta & 127)*512 + (size_t)(t0 + tc))*256;
        } else {
            a16[f] = A16 + (size_t)m*256;
        }
    }

    for (int k0 = 0; k0 < 256; k0 += 16){
        uint2 a_[4], b_[4];
        #pragma unroll
        for (int f = 0; f < 4; f++){
            if (A_FP32){
                float4 v = *(const float4*)(a32[f] + k0 + lk*4);
                a_[f] = make_uint2(pack2(v.x, v.y), pack2(v.z, v.w));
            } else {
                a_[f] = *(const uint2*)(a16[f] + k0 + lk*4);
            }
        }
        #pragma unroll
        for (int f = 0; f < 4; f++)
            b_[f] = *(const uint2*)&Blds[wn + f*16 + lr][k0 + lk*4];
        #pragma unroll
        for (int fm = 0; fm < 4; fm++)
            #pragma unroll
            for (int fn = 0; fn < 4; fn++)
                acc[fm][fn] = __builtin_amdgcn_mfma_f32_16x16x16f16(
                    __builtin_bit_cast(h4v, a_[fm]),
                    __builtin_bit_cast(h4v, b_[fn]),
                    acc[fm][fn], 0, 0, 0);
    }

    // D[row = 4*lk + i][col = lr]
    #pragma unroll
    for (int fm = 0; fm < 4; fm++){
        #pragma unroll
        for (int i = 0; i < 4; i++){
            int m = m0 + wm + fm*16 + lk*4 + i;
            size_t rowoff = (size_t)m*1024 + n0 + wn;
            #pragma unroll
            for (int fn = 0; fn < 4; fn++)
                Cout[rowoff + fn*16 + lr] = f2h_bits(acc[fm][fn][i]);
        }
    }
}

// ---------- persistent LSTM recurrence over one T-chunk ----------
// One workgroup per beta (256 wgs), 512 threads. Lane L owns gate rows 2L, 2L+1.
// Whh pairs 0..95 in registers (192 VGPR/lane), pairs 96..127 in LDS (128 KB).
__global__ __launch_bounds__(512, 2) void lstm_rec(
        const u16* __restrict__ xg,      // [beta][tc][1024] fp16 (chunk)
        const u32* __restrict__ whhT,    // [128][1024] this layer
        const float* __restrict__ bias,  // [1024]
        u16* __restrict__ hseq,          // [beta][tc][256] chunk, or null
        u16* __restrict__ h_state,       // [256][256] fp16
        float* __restrict__ c_state,     // [256][256] f32
        int Tc, int write_seq, int first){
    __shared__ u32 wlds[32][1024];
    __shared__ alignas(16) u16 hbuf[256];
    __shared__ float gbuf[1024];

    const int L    = threadIdx.x;        // 0..511
    const int beta = blockIdx.x;         // 0..255

    u32 w0[96], w1[96];
    #pragma unroll
    for (int p = 0; p < 96; p++){
        uint2 v = *(const uint2*)&whhT[(size_t)p*1024 + 2*L];
        w0[p] = v.x; w1[p] = v.y;
    }
    for (int i = 0; i < 64; i++){
        int idx = i*512 + L;
        ((u32*)wlds)[idx] = whhT[96*1024 + idx];
    }
    const float b0 = bias[2*L], b1 = bias[2*L+1];
    float c = 0.f;
    if (L < 256){
        hbuf[L] = first ? (u16)0 : h_state[(size_t)beta*256 + L];
        if (!first) c = c_state[(size_t)beta*256 + L];
    }
    __syncthreads();

    const u32* xgu = (const u32*)xg + ((size_t)beta * Tc) * 512;

    for (int tc = 0; tc < Tc; tc++){
        u32 xp = xgu[(size_t)tc*512 + L];
        h2v xh = __builtin_bit_cast(h2v, xp);
        float acc0 = b0 + (float)xh[0];
        float acc1 = b1 + (float)xh[1];

        const uint4* hv = (const uint4*)hbuf;
        #pragma unroll
        for (int q = 0; q < 24; q++){            // pairs 0..95 (register weights)
            uint4 hh = hv[q];
            acc0 = fdot2(w0[4*q+0], hh.x, acc0); acc1 = fdot2(w1[4*q+0], hh.x, acc1);
            acc0 = fdot2(w0[4*q+1], hh.y, acc0); acc1 = fdot2(w1[4*q+1], hh.y, acc1);
            acc0 = fdot2(w0[4*q+2], hh.z, acc0); acc1 = fdot2(w1[4*q+2], hh.z, acc1);
            acc0 = fdot2(w0[4*q+3], hh.w, acc0); acc1 = fdot2(w1[4*q+3], hh.w, acc1);
        }
        #pragma unroll
        for (int q = 24; q < 32; q++){           // pairs 96..127 (LDS weights)
            uint4 hh = hv[q];
            { uint2 wv = *(const uint2*)&wlds[4*q-96+0][2*L]; acc0 = fdot2(wv.x, hh.x, acc0); acc1 = fdot2(wv.y, hh.x, acc1); }
            { uint2 wv = *(const uint2*)&wlds[4*q-96+1][2*L]; acc0 = fdot2(wv.x, hh.y, acc0); acc1 = fdot2(wv.y, hh.y, acc1); }
            { uint2 wv = *(const uint2*)&wlds[4*q-96+2][2*L]; acc0 = fdot2(wv.x, hh.z, acc0); acc1 = fdot2(wv.y, hh.z, acc1); }
            { uint2 wv = *(const uint2*)&wlds[4*q-96+3][2*L]; acc0 = fdot2(wv.x, hh.w, acc0); acc1 = fdot2(wv.y, hh.w, acc1); }
        }
        *(float2*)&gbuf[2*L] = make_float2(acc0, acc1);
        __syncthreads();

        if (L < 256){
            float gi = gbuf[L],       gf = gbuf[256+L];
            float gg = gbuf[512+L],   go = gbuf[768+L];
            float iv = sigm(gi), fv = sigm(gf), gv = tanh_fast(gg), ov = sigm(go);
            c = fv*c + iv*gv;
            float h = ov * tanh_fast(c);
            u16 hb = f2h_bits(h);
            hbuf[L] = hb;
            if (write_seq) hseq[((size_t)beta*Tc + tc)*256 + L] = hb;
        }
        __syncthreads();
    }

    if (L < 256){
        h_state[(size_t)beta*256 + L] = hbuf[L];
        c_state[(size_t)beta*256 + L] = c;
    }
}

// ---------- final FC: out[r][k] = relu(hn[r]) . fc_w[k] + fc_b[k] ----------
// r = inp*256 + l*128 + b ; h_state layout [l][beta][j], beta = inp*128+b
__global__ void fc_out(const u16* __restrict__ hlast,
                       const float* __restrict__ fcw,   // [5][256]
                       const float* __restrict__ fcb,   // [5]
                       float* __restrict__ out){        // [512][5]
    int r = blockIdx.x;
    int lane = threadIdx.x;      // 0..63
    int inp = r >> 8, rem = r & 255, l = rem >> 7, b = rem & 127;
    int beta = inp*128 + b;
    const u16* h = hlast + ((size_t)l*256 + beta)*256;

    int j0 = lane * 4;
    uint2 hb = *(const uint2*)(h + j0);
    h2v p0 = __builtin_bit_cast(h2v, hb.x), p1 = __builtin_bit_cast(h2v, hb.y);
    float hv0 = fmaxf((float)p0[0], 0.f);
    float hv1 = fmaxf((float)p0[1], 0.f);
    float hv2 = fmaxf((float)p1[0], 0.f);
    float hv3 = fmaxf((float)p1[1], 0.f);

    float acc[5];
    #pragma unroll
    for (int k = 0; k < 5; k++){
        float4 w = *(const float4*)(fcw + k*256 + j0);
        acc[k] = hv0*w.x + hv1*w.y + hv2*w.z + hv3*w.w;
    }
    #pragma unroll
    for (int k = 0; k < 5; k++)
        #pragma unroll
        for (int off = 32; off > 0; off >>= 1)
            acc[k] += __shfl_xor(acc[k], off);
    if (lane == 0){
        #pragma unroll
        for (int k = 0; k < 5; k++)
            out[(size_t)r*5 + k] = acc[k] + fcb[k];
    }
}

// ---------- host launch ----------
extern "C" void kernel_launch(void* const* d_in, const int* in_sizes, int n_in,
                              void* d_out, int out_size, void* d_ws, size_t ws_size,
                              hipStream_t stream) {
    const float* in1 = (const float*)d_in[0];
    const float* in2 = (const float*)d_in[1];
    const float* Wih = (const float*)d_in[2];
    const float* Whh = (const float*)d_in[3];
    const float* bih = (const float*)d_in[4];
    const float* bhh = (const float*)d_in[5];
    const float* fcw = (const float*)d_in[6];
    const float* fcb = (const float*)d_in[7];
    float* out = (float*)d_out;

    // fixed workspace region (~3 MB)
    char* ws = (char*)d_ws;
    u16*   wih16   = (u16*)  (ws + 0x000000);   // [2][1024][256] fp16 (1 MB)
    u32*   whhT    = (u32*)  (ws + 0x100000);   // [2][128][1024] u32  (1 MB)
    float* bias    = (float*)(ws + 0x200000);   // [2][1024]
    u16*   h_state = (u16*)  (ws + 0x202000);   // [2][256][256] fp16 (256 KB)
    float* c_state = (float*)(ws + 0x242000);   // [2][256][256] f32  (512 KB)
    const size_t chunk_off = 0x300000;

    // adaptive T-chunk: xg chunk = Tc*512KB, hseq chunk = Tc*128KB
    int Tc = 8;
    for (int cand = 512; cand >= 8; cand >>= 1){
        if (chunk_off + (size_t)cand * 655360ull <= ws_size){ Tc = cand; break; }
    }
    int lgTc = 31 - __builtin_clz((u32)Tc);
    u16* xgc = (u16*)(ws + chunk_off);
    u16* hsc = (u16*)(ws + chunk_off + (size_t)Tc * 524288ull);

    cvt_weights<<<1024, 256, 0, stream>>>(Wih, Whh, bih, bhh,
                                          (u32*)wih16, whhT, bias);

    const int nch = 512 / Tc;
    dim3 pg(8, 2*Tc);   // N-tiles fastest -> A-panel reuse hits L2/L3
    for (int k = 0; k < nch; k++){
        int t0 = k * Tc;
        // layer 0
        proj_gemm<1><<<pg, 256, 0, stream>>>(in1, in2, (const u16*)nullptr,
                                             wih16, xgc, t0, lgTc);
        lstm_rec<<<256, 512, 0, stream>>>((const u16*)xgc, whhT, bias,
                                          hsc, h_state, c_state,
                                          Tc, 1, k == 0);
        // layer 1
        proj_gemm<0><<<pg, 256, 0, stream>>>((const float*)nullptr, (const float*)nullptr,
                                             (const u16*)hsc,
                                             wih16 + 262144, xgc, 0, lgTc);
        lstm_rec<<<256, 512, 0, stream>>>((const u16*)xgc, whhT + 131072, bias + 1024,
                                          (u16*)nullptr, h_state + 65536, c_state + 65536,
                                          Tc, 0, k == 0);
    }
    fc_out<<<512, 64, 0, stream>>>(h_state, fcw, fcb, out);
}

// Round 3
// 2781.748 us; speedup vs baseline: 1.1450x; 1.1450x over previous
//
#include <hip/hip_runtime.h>
#include <hip/hip_fp16.h>

typedef unsigned int  u32;
typedef unsigned short u16;

typedef _Float16 h2v __attribute__((ext_vector_type(2)));
typedef _Float16 h4v __attribute__((ext_vector_type(4)));
typedef float    f4v __attribute__((ext_vector_type(4)));

// ---------- helpers ----------
static __device__ __forceinline__ u16 f2h_bits(float x){
    _Float16 h = (_Float16)x;
    return __builtin_bit_cast(u16, h);
}
static __device__ __forceinline__ u32 pack2(float a, float b){
    return (u32)f2h_bits(a) | ((u32)f2h_bits(b) << 16);
}
static __device__ __forceinline__ float fdot2(u32 w, u32 h, float acc){
#if __has_builtin(__builtin_amdgcn_fdot2)
    return __builtin_amdgcn_fdot2(__builtin_bit_cast(h2v, w),
                                  __builtin_bit_cast(h2v, h), acc, false);
#else
    h2v wv = __builtin_bit_cast(h2v, w), hv = __builtin_bit_cast(h2v, h);
    return acc + (float)wv[0]*(float)hv[0] + (float)wv[1]*(float)hv[1];
#endif
}
static __device__ __forceinline__ float sigm(float x){
    return 1.f / (1.f + __expf(-x));
}
static __device__ __forceinline__ float tanh_fast(float x){
    return 1.f - 2.f / (__expf(2.f*x) + 1.f);
}

// B=128, T=512, D=H=256, 4H=1024; beta in [0,256): beta<128 -> input1, else input2

// ---------- kernel: convert weights ----------
// wih16: [l][g][d] fp16 (flat cast of W_ih)
// whhT : [l][p][r] u32, p = column-pair (0..127), r = gate row (0..1023)
//        whhT[l][p][r] packs (Whh[l][r][2p], Whh[l][r][2p+1])
// bias : [l][g] = b_ih + b_hh
__global__ void cvt_weights(const float* __restrict__ Wih,
                            const float* __restrict__ Whh,
                            const float* __restrict__ bih,
                            const float* __restrict__ bhh,
                            u32* __restrict__ wih16u,   // 262144 u32
                            u32* __restrict__ whhT,     // 262144 u32
                            float* __restrict__ bias){  // 2048
    u32 e = blockIdx.x * blockDim.x + threadIdx.x;      // 0 .. 262143
    {
        float2 v = ((const float2*)Wih)[e];
        wih16u[e] = pack2(v.x, v.y);
    }
    {
        u32 l = e >> 17, rem = e & 131071u;
        u32 p = rem >> 10, r = rem & 1023u;
        float2 v = ((const float2*)Whh)[(size_t)(l*1024u + r)*128u + p];
        whhT[e] = pack2(v.x, v.y);
    }
    if (e < 2048u) bias[e] = bih[e] + bhh[e];
}

// ---------- projection GEMM:  C[Mc,1024] = A[Mc,256] * B[1024,256]^T ----------
template<int A_FP32>
__global__ __launch_bounds__(256) void proj_gemm(
        const float* __restrict__ in1, const float* __restrict__ in2,
        const u16*  __restrict__ A16,
        const u16*  __restrict__ Bw,      // [1024][256] fp16 = W_ih[l]
        u16*        __restrict__ Cout,    // [Mc][1024] fp16
        int t0, int lgTc){
    __shared__ u16 Blds[128][260];        // +4 halves pad
    const int tid = threadIdx.x;
    const int n0 = blockIdx.x * 128;
    const int m0 = blockIdx.y * 128;

    {   // stage B tile (128 rows x 128 u32), coalesced
        const u32* src = (const u32*)Bw;
        #pragma unroll
        for (int i = 0; i < 64; i++){
            int idx = i*256 + tid;
            int r  = idx >> 7;
            int cu = idx & 127;
            u32 v = src[(size_t)(n0 + r)*128 + cu];
            *(u32*)&Blds[r][cu*2] = v;
        }
    }
    __syncthreads();

    const int l   = tid & 63;
    const int wid = tid >> 6;
    const int wm = (wid >> 1) * 64;
    const int wn = (wid & 1) * 64;
    const int lr = l & 15;
    const int lk = l >> 4;

    f4v acc[4][4] = {};

    const float* a32[4];
    const u16*   a16[4];
    #pragma unroll
    for (int f = 0; f < 4; f++){
        int m = m0 + wm + f*16 + lr;
        if (A_FP32){
            int beta = m >> lgTc;
            int tc   = m & ((1 << lgTc) - 1);
            const float* base = (beta < 128) ? in1 : in2;
            a32[f] = base + ((size_t)(beta & 127)*512 + (size_t)(t0 + tc))*256;
        } else {
            a16[f] = A16 + (size_t)m*256;
        }
    }

    for (int k0 = 0; k0 < 256; k0 += 16){
        uint2 a_[4], b_[4];
        #pragma unroll
        for (int f = 0; f < 4; f++){
            if (A_FP32){
                float4 v = *(const float4*)(a32[f] + k0 + lk*4);
                a_[f] = make_uint2(pack2(v.x, v.y), pack2(v.z, v.w));
            } else {
                a_[f] = *(const uint2*)(a16[f] + k0 + lk*4);
            }
        }
        #pragma unroll
        for (int f = 0; f < 4; f++)
            b_[f] = *(const uint2*)&Blds[wn + f*16 + lr][k0 + lk*4];
        #pragma unroll
        for (int fm = 0; fm < 4; fm++)
            #pragma unroll
            for (int fn = 0; fn < 4; fn++)
                acc[fm][fn] = __builtin_amdgcn_mfma_f32_16x16x16f16(
                    __builtin_bit_cast(h4v, a_[fm]),
                    __builtin_bit_cast(h4v, b_[fn]),
                    acc[fm][fn], 0, 0, 0);
    }

    // D[row = 4*lk + i][col = lr]
    #pragma unroll
    for (int fm = 0; fm < 4; fm++){
        #pragma unroll
        for (int i = 0; i < 4; i++){
            int m = m0 + wm + fm*16 + lk*4 + i;
            size_t rowoff = (size_t)m*1024 + n0 + wn;
            #pragma unroll
            for (int fn = 0; fn < 4; fn++)
                Cout[rowoff + fn*16 + lr] = f2h_bits(acc[fm][fn][i]);
        }
    }
}

// ---------- persistent LSTM recurrence over one T-chunk ----------
// 1024 threads/wg, one gate row per thread. 256 wgs (one per beta).
// Row weights: pairs 0..91 in VGPRs (92 regs), pairs 92..127 in LDS [row][36]
// (144B row stride, read as 9 x ds_read_b128). 16 waves/CU @ <=128 VGPR.
#define NREG 92
#define NLDSP 36   // = 128 - NREG, pairs per row in LDS

__global__ __launch_bounds__(1024, 4) void lstm_rec(
        const u16* __restrict__ xg,      // [beta][tc][1024] fp16 (chunk)
        const u32* __restrict__ whhT,    // [128][1024] this layer
        const float* __restrict__ bias,  // [1024]
        u16* __restrict__ hseq,          // [beta][tc][256] chunk, or null
        u16* __restrict__ h_state,       // [256][256] fp16
        float* __restrict__ c_state,     // [256][256] f32
        int Tc, int write_seq, int first){
    __shared__ u32 wlds[1024][NLDSP];           // 144 KB
    __shared__ alignas(16) u16 hbuf[256];
    __shared__ float gbuf[1024];

    const int L    = threadIdx.x;        // 0..1023 = gate row
    const int beta = blockIdx.x;         // 0..255

    // register weights: pairs 0..91 of row L
    u32 w[NREG];
    #pragma unroll
    for (int p = 0; p < NREG; p++)
        w[p] = whhT[(size_t)p*1024 + L];
    // LDS weights: pairs 92..127, row-major
    #pragma unroll
    for (int i = 0; i < NLDSP; i++)
        wlds[L][i] = whhT[(size_t)(NREG + i)*1024 + L];

    const float bs = bias[L];
    float c = 0.f;
    if (L < 256){
        hbuf[L] = first ? (u16)0 : h_state[(size_t)beta*256 + L];
        if (!first) c = c_state[(size_t)beta*256 + L];
    }
    __syncthreads();

    const u16* xr = xg + (size_t)beta * Tc * 1024 + L;
    u16 xcur = xr[0];

    for (int tc = 0; tc < Tc; tc++){
        u16 xnext = (tc + 1 < Tc) ? xr[(size_t)(tc+1)*1024] : (u16)0;

        float accA = bs + (float)__builtin_bit_cast(_Float16, xcur);
        float accB = 0.f;

        const uint4* hv = (const uint4*)hbuf;
        const uint4* wl = (const uint4*)&wlds[L][0];
        #pragma unroll
        for (int q = 0; q < 23; q++){            // pairs 0..91 (register weights)
            uint4 hh = hv[q];
            accA = fdot2(w[4*q+0], hh.x, accA);
            accB = fdot2(w[4*q+1], hh.y, accB);
            accA = fdot2(w[4*q+2], hh.z, accA);
            accB = fdot2(w[4*q+3], hh.w, accB);
        }
        #pragma unroll
        for (int j = 0; j < 9; j++){             // pairs 92..127 (LDS weights)
            uint4 hh = hv[23 + j];
            uint4 ww = wl[j];
            accA = fdot2(ww.x, hh.x, accA);
            accB = fdot2(ww.y, hh.y, accB);
            accA = fdot2(ww.z, hh.z, accA);
            accB = fdot2(ww.w, hh.w, accB);
        }
        gbuf[L] = accA + accB;
        xcur = xnext;
        __syncthreads();

        if (L < 256){
            float gi = gbuf[L],       gf = gbuf[256+L];
            float gg = gbuf[512+L],   go = gbuf[768+L];
            float iv = sigm(gi), fv = sigm(gf), gv = tanh_fast(gg), ov = sigm(go);
            c = fv*c + iv*gv;
            float h = ov * tanh_fast(c);
            u16 hb = f2h_bits(h);
            hbuf[L] = hb;
            if (write_seq) hseq[((size_t)beta*Tc + tc)*256 + L] = hb;
        }
        __syncthreads();
    }

    if (L < 256){
        h_state[(size_t)beta*256 + L] = hbuf[L];
        c_state[(size_t)beta*256 + L] = c;
    }
}

// ---------- final FC: out[r][k] = relu(hn[r]) . fc_w[k] + fc_b[k] ----------
__global__ void fc_out(const u16* __restrict__ hlast,
                       const float* __restrict__ fcw,   // [5][256]
                       const float* __restrict__ fcb,   // [5]
                       float* __restrict__ out){        // [512][5]
    int r = blockIdx.x;
    int lane = threadIdx.x;      // 0..63
    int inp = r >> 8, rem = r & 255, l = rem >> 7, b = rem & 127;
    int beta = inp*128 + b;
    const u16* h = hlast + ((size_t)l*256 + beta)*256;

    int j0 = lane * 4;
    uint2 hb = *(const uint2*)(h + j0);
    h2v p0 = __builtin_bit_cast(h2v, hb.x), p1 = __builtin_bit_cast(h2v, hb.y);
    float hv0 = fmaxf((float)p0[0], 0.f);
    float hv1 = fmaxf((float)p0[1], 0.f);
    float hv2 = fmaxf((float)p1[0], 0.f);
    float hv3 = fmaxf((float)p1[1], 0.f);

    float acc[5];
    #pragma unroll
    for (int k = 0; k < 5; k++){
        float4 w = *(const float4*)(fcw + k*256 + j0);
        acc[k] = hv0*w.x + hv1*w.y + hv2*w.z + hv3*w.w;
    }
    #pragma unroll
    for (int k = 0; k < 5; k++)
        #pragma unroll
        for (int off = 32; off > 0; off >>= 1)
            acc[k] += __shfl_xor(acc[k], off);
    if (lane == 0){
        #pragma unroll
        for (int k = 0; k < 5; k++)
            out[(size_t)r*5 + k] = acc[k] + fcb[k];
    }
}

// ---------- host launch ----------
extern "C" void kernel_launch(void* const* d_in, const int* in_sizes, int n_in,
                              void* d_out, int out_size, void* d_ws, size_t ws_size,
                              hipStream_t stream) {
    const float* in1 = (const float*)d_in[0];
    const float* in2 = (const float*)d_in[1];
    const float* Wih = (const float*)d_in[2];
    const float* Whh = (const float*)d_in[3];
    const float* bih = (const float*)d_in[4];
    const float* bhh = (const float*)d_in[5];
    const float* fcw = (const float*)d_in[6];
    const float* fcb = (const float*)d_in[7];
    float* out = (float*)d_out;

    // fixed workspace region (~3 MB)
    char* ws = (char*)d_ws;
    u16*   wih16   = (u16*)  (ws + 0x000000);   // [2][1024][256] fp16 (1 MB)
    u32*   whhT    = (u32*)  (ws + 0x100000);   // [2][128][1024] u32  (1 MB)
    float* bias    = (float*)(ws + 0x200000);   // [2][1024]
    u16*   h_state = (u16*)  (ws + 0x202000);   // [2][256][256] fp16 (256 KB)
    float* c_state = (float*)(ws + 0x242000);   // [2][256][256] f32  (512 KB)
    const size_t chunk_off = 0x300000;

    // adaptive T-chunk: xg chunk = Tc*512KB, hseq chunk = Tc*128KB
    int Tc = 8;
    for (int cand = 512; cand >= 8; cand >>= 1){
        if (chunk_off + (size_t)cand * 655360ull <= ws_size){ Tc = cand; break; }
    }
    int lgTc = 31 - __builtin_clz((u32)Tc);
    u16* xgc = (u16*)(ws + chunk_off);
    u16* hsc = (u16*)(ws + chunk_off + (size_t)Tc * 524288ull);

    cvt_weights<<<1024, 256, 0, stream>>>(Wih, Whh, bih, bhh,
                                          (u32*)wih16, whhT, bias);

    const int nch = 512 / Tc;
    dim3 pg(8, 2*Tc);   // N-tiles fastest -> A-panel reuse hits L2/L3
    for (int k = 0; k < nch; k++){
        int t0 = k * Tc;
        // layer 0
        proj_gemm<1><<<pg, 256, 0, stream>>>(in1, in2, (const u16*)nullptr,
                                             wih16, xgc, t0, lgTc);
        lstm_rec<<<256, 1024, 0, stream>>>((const u16*)xgc, whhT, bias,
                                           hsc, h_state, c_state,
                                           Tc, 1, k == 0);
        // layer 1
        proj_gemm<0><<<pg, 256, 0, stream>>>((const float*)nullptr, (const float*)nullptr,
                                             (const u16*)hsc,
                                             wih16 + 262144, xgc, 0, lgTc);
        lstm_rec<<<256, 1024, 0, stream>>>((const u16*)xgc, whhT + 131072, bias + 1024,
                                           (u16*)nullptr, h_state + 65536, c_state + 65536,
                                           Tc, 0, k == 0);
    }
    fc_out<<<512, 64, 0, stream>>>(h_state, fcw, fcb, out);
}